// Round 8
// baseline (396.743 us; speedup 1.0000x reference)
//
#include <hip/hip_runtime.h>
#include <math.h>

typedef unsigned int u32;
typedef unsigned long long u64;

#define BB 4
#define AA 262144              // 1<<18
#define NN (BB*AA)
#define PRE 4000
#define POST 1000
#define CAP 4096               // crow/nbox row stride
#define CAPR 5632              // key slots per batch: G [0,4000) + E [4000,5632)
#define MASKW 64
#define NBLK 63                // ceil(4000/64)

// ---- workspace layout (bytes) ----
// [0, ZERO_END) cleared by ONE memset: hists + pfx + counters + keys.
static const size_t OFF_HIST = 0;                          // u32[4][65536] = 1 MiB
static const size_t OFF_PFX  = 1048576;                    // u32[4] (padded 128B)
static const size_t OFF_CNTG = 1048704;                    // int, stride 32 ints x4
static const size_t OFF_CNTE = 1049216;                    // int, stride 32 ints x4
static const size_t CTRL_END = 1049728;
static const size_t OFF_KEYS = CTRL_END;                   // u64[4][5632] = 176 KiB
static const size_t ZERO_END = OFF_KEYS + (size_t)BB*CAPR*8;
static const size_t OFF_CROW = ZERO_END;                           // float[4][4096][8]
static const size_t OFF_NBOX = OFF_CROW + (size_t)BB*CAP*8*4;
static const size_t OFF_MASK = OFF_NBOX + (size_t)BB*CAP*8*4;      // u64[4][64][4000] = 8 MB

// f32 sigmoid via correctly-rounded double exp (bit-exact, order == value order).
__device__ __forceinline__ u32 sigmoid_bits(float x) {
  float e = (float)exp(-(double)x);
  float s = 1.0f / (1.0f + e);
  return __float_as_uint(s);     // s in (0,1): bits > 0
}

// Monotone u32 transform of a float's bits (sigmoid is monotone in x, so
// order-by-x == order-by-score; lets hist/compact skip the expensive exp).
__device__ __forceinline__ u32 mono_bits(float x) {
  u32 f = __float_as_uint(x);
  return (f & 0x80000000u) ? ~f : (f | 0x80000000u);
}

// ---- single-pass 16-bit histogram over transformed objectness ----
// 1M global atomics over 65536 bins/batch: ~16/bin, negligible contention.
__global__ void k_hist16(const float* __restrict__ obj, u32* __restrict__ hist) {
  size_t g = (size_t)blockIdx.x*256 + threadIdx.x;
  u32 tt = mono_bits(obj[g]);
  int b = (int)(g >> 18);
  atomicAdd(&hist[((size_t)b << 16) + (tt >> 16)], 1u);
}

// ---- resolve: per batch find 16-bit bin P of the 4000th-largest ----
// Guarantees: count(bin > P) <= 3999, count(bin >= P) >= 4000.
__global__ __launch_bounds__(256) void k_resolve(const u32* __restrict__ hist,
                                                 u32* __restrict__ pfx) {
  int b = blockIdx.x, t = threadIdx.x;
  const u32* h = hist + ((size_t)b << 16);
  __shared__ u32 seg[256];
  __shared__ int chosen;
  __shared__ u32 before;
  __shared__ u32 segbins[256];
  u32 s = 0;
  const uint4* h4 = (const uint4*)(h + t*256);
  #pragma unroll 8
  for (int k = 0; k < 64; ++k) { uint4 v = h4[k]; s += v.x + v.y + v.z + v.w; }
  seg[t] = s;
  __syncthreads();
  if (t == 0) {
    u32 acc = 0; int cs = 0; u32 bf = 0;
    for (int i = 255; i >= 0; --i) {          // descending value order
      u32 c = seg[i];
      if (acc + c >= (u32)PRE) { cs = i; bf = acc; break; }
      acc += c;
    }
    chosen = cs; before = bf;
  }
  __syncthreads();
  segbins[t] = h[chosen*256 + t];             // coalesced stage of chosen segment
  __syncthreads();
  if (t == 0) {
    u32 acc = before; int P = chosen*256;
    for (int bin = chosen*256 + 255; bin >= chosen*256; --bin) {
      u32 c = segbins[bin - chosen*256];
      if (acc + c >= (u32)PRE) { P = bin; break; }
      acc += c;
    }
    pfx[b] = (u32)P;
  }
}

// ---- compact candidates ----
// R7 POST-MORTEM: 16-bit bins are uniform in BIT space (128 bins/octave), so
// the P bin holds ~385 elements, count(>=P) overflowed CAP=4096 and E-slots
// (written downward from the top) clobbered G keys. Fix: DISJOINT regions —
// G (bin>P, provably <=3999) in [0,4000); E (bins P-1 and P, ~770 expected,
// capacity 1632 ~ 30 sigma) in [4000,5632). Admitting P-1 too guarantees any
// f32-sigmoid tie partner of a top-4000 element is admitted (bin width at the
// threshold >> sigmoid ulp), so exact key ranking reproduces top_k exactly.
// Sigmoid computed only for admitted candidates (~4.8K of 1M).
__global__ __launch_bounds__(256) void k_compact(const float* __restrict__ obj,
                                                 const u32* __restrict__ pfx,
                                                 int* __restrict__ cntG,
                                                 int* __restrict__ cntE,
                                                 u64* __restrict__ keys) {
  __shared__ u64 st[2048];            // G from front, E from back
  __shared__ int nG, nE, baseG, baseE;
  int tid = threadIdx.x;
  if (tid == 0) { nG = 0; nE = 0; }
  __syncthreads();
  size_t blockBase = (size_t)blockIdx.x * 4096;
  int b = (int)(blockBase >> 18);
  u32 P = pfx[b];
  for (int k = 0; k < 16; ++k) {
    size_t g = blockBase + (size_t)k*256 + tid;
    float x = obj[g];
    u32 tb = mono_bits(x) >> 16;
    if (tb + 1u >= P) {               // admit bins P-1, P, >P
      u32 m = sigmoid_bits(x);
      u64 key = ((u64)m << 32) | (u64)(AA - 1 - (u32)(g & (AA - 1)));
      if (tb > P) { int p = atomicAdd(&nG, 1); if (p < 1536) st[p] = key; }
      else        { int p = atomicAdd(&nE, 1); if (p < 512) st[2047 - p] = key; }
    }
  }
  __syncthreads();
  int ng = nG < 1536 ? nG : 1536;
  int ne = nE < 512 ? nE : 512;
  if (tid == 0) baseG = atomicAdd(&cntG[b*32], ng);
  if (tid == 1) baseE = atomicAdd(&cntE[b*32], ne);
  __syncthreads();
  for (int i = tid; i < ng; i += 256) {
    int p = baseG + i;
    if (p < 4000) keys[(size_t)b*CAPR + p] = st[i];          // G region [0,4000)
  }
  for (int i = tid; i < ne; i += 256) {
    int p = baseE + i;
    if (p < CAPR - 4000) keys[(size_t)b*CAPR + 4000 + p] = st[2047 - i]; // E region
  }
}

// ---- rank + decode fused ----
// Keys unique -> sorted position == #{greater keys}. Batch-16 LDS reads keep
// 16 ds_read_b128 in flight per lgkmcnt wait (R6 was 1-deep: latency-bound).
__global__ __launch_bounds__(64) void k_rank(const u64* __restrict__ keys,
                                             const float* __restrict__ reg,
                                             const float* __restrict__ anc,
                                             float* __restrict__ crow,
                                             float* __restrict__ nbox) {
  __shared__ __align__(16) u64 sk[CAPR];   // 44 KB
  int b = blockIdx.y;
  const ulonglong2* kb2 = (const ulonglong2*)(keys + (size_t)b*CAPR);
  ulonglong2* sk2 = (ulonglong2*)sk;
  for (int t = threadIdx.x; t < CAPR/2; t += 64) sk2[t] = kb2[t];
  __syncthreads();
  int slot = blockIdx.x*64 + threadIdx.x;
  u64 myk = sk[slot];
  int rank = 0;
  const ulonglong2* p2 = (const ulonglong2*)sk;
  for (int base = 0; base < CAPR/2; base += 16) {   // 176 batches
    ulonglong2 v[16];
    #pragma unroll
    for (int k = 0; k < 16; ++k) v[k] = p2[base + k];
    #pragma unroll
    for (int k = 0; k < 16; ++k)
      rank += (int)(v[k].x > myk) + (int)(v[k].y > myk);
  }
  if (myk == 0 || rank >= PRE) return;    // padding or beyond top-4000
  u32 m = (u32)(myk >> 32);
  int idx = AA - 1 - (int)(myk & 0xFFFFFFFFull);
  float score = __uint_as_float(m);
  size_t g = ((size_t)b << 18) + (size_t)idx;
  const float* rg = reg + g*7;
  const float* an = anc + g*7;
  float xa=an[0], ya=an[1], za=an[2], wa=an[3], la=an[4], ha=an[5], ra=an[6];
  float dx=rg[0], dy=rg[1], dz=rg[2], dw=rg[3], dl=rg[4], dh=rg[5], dr=rg[6];
  float diag = sqrtf(wa*wa + la*la);
  float x = dx*diag + xa;
  float y = dy*diag + ya;
  float z = dz*ha + za;
  float w = expf(dw)*wa;
  float l = expf(dl)*la;
  float h = expf(dh)*ha;
  float r = dr + ra;
  float* cr = crow + ((size_t)b*CAP + rank)*8;
  cr[0]=x; cr[1]=y; cr[2]=z; cr[3]=w; cr[4]=l; cr[5]=h; cr[6]=r; cr[7]=score;
  float sx = fmaxf(w, 0.2f), sy = fmaxf(l, 0.2f), sz = fmaxf(h, 0.2f);
  float* nb = nbox + ((size_t)b*CAP + rank)*8;
  nb[0]=x - sx*0.5f; nb[1]=y - sy*0.5f; nb[2]=z;
  nb[3]=x + sx*0.5f; nb[4]=y + sy*0.5f; nb[5]=z + sz;
  nb[6]=sx*sy*sz;   nb[7]=0.f;
}

// ---- suppression bitmask, col-major mask[b][word c][row i] ----
__global__ __launch_bounds__(256) void k_mask(const float* __restrict__ nbox,
                                              u64* __restrict__ mask) {
  int c = blockIdx.x;            // word/column block 0..62
  int R = blockIdx.y;            // 256-row tile 0..15
  int b = blockIdx.z;
  if (c < R*4) return;           // tile fully below diagonal: words never read
  __shared__ float4 ca4[64], cb4[64];
  int t = threadIdx.x;
  int j0 = c*64;
  if (t < 64) {
    int j = j0 + t; int jc = j < PRE ? j : 0;
    const float4* p = (const float4*)(nbox + ((size_t)b*CAP + jc)*8);
    ca4[t] = p[0]; cb4[t] = p[1];
  }
  __syncthreads();
  int i = R*256 + t;
  if (i >= PRE) return;
  const float4* rp = (const float4*)(nbox + ((size_t)b*CAP + i)*8);
  float4 A = rp[0], Bv = rp[1];  // A = lo.xyz, hi.x ; Bv = hi.y, hi.z, vol, pad
  u64 bits = 0;
  #pragma unroll
  for (int jj = 0; jj < 64; ++jj) {
    float4 C = ca4[jj], D = cb4[jj];
    float d0 = fminf(A.w,  C.w) - fmaxf(A.x, C.x);
    float d1 = fminf(Bv.x, D.x) - fmaxf(A.y, C.y);
    float d2 = fminf(Bv.y, D.y) - fmaxf(A.z, C.z);
    float inter = fmaxf(d0, 0.f) * fmaxf(d1, 0.f) * fmaxf(d2, 0.f);
    float uni = Bv.z + D.z - inter;
    if (inter > 0.3f * uni) bits |= (1ull << jj);
  }
  int vcols = PRE - j0;                                  // >= 32 for c <= 62
  if (vcols < 64) bits &= ((1ull << vcols) - 1ull);      // clear cols >= PRE
  if (j0 <= i) {                                          // clear cols j <= i
    int d = i - j0;
    if (d >= 63) bits = 0;
    else bits &= ~((2ull << d) - 1ull);
  }
  mask[((size_t)b*MASKW + c)*PRE + i] = bits;
}

// ---- greedy NMS reduce + fused output gather: one wave per batch ----
// (R4 lesson: ONE 64-u64 register buffer only — two spill at the 256-VGPR cap.)
__global__ __launch_bounds__(64) void k_reduce(const u64* __restrict__ mask,
                                               const float* __restrict__ crow,
                                               float* __restrict__ out) {
  __shared__ int sel_lds[POST];
  int b = blockIdx.x, lane = threadIdx.x;
  const u64* col = mask + ((size_t)b*MASKW + lane)*PRE;   // this lane's word-column
  u64 removed = 0;
  int kc = 0;
  for (int q = 0; q < NBLK; ++q) {
    u64 buf[64];
    bool act = lane >= q;        // words < q of these rows were never written
    if (q < NBLK - 1) {          // rows q*64 .. q*64+63 all < PRE
      const ulonglong2* p = (const ulonglong2*)(col + q*64);
      #pragma unroll
      for (int jj = 0; jj < 32; ++jj) {
        ulonglong2 v; v.x = 0; v.y = 0;
        if (act) v = p[jj];
        buf[2*jj] = v.x; buf[2*jj+1] = v.y;
      }
    } else {                     // last block: guard rows >= PRE
      #pragma unroll
      for (int jj = 0; jj < 64; ++jj) {
        int row = q*64 + jj;
        u64 v = 0;
        if (act && row < PRE) v = col[row];
        buf[jj] = v;
      }
    }
    int nv = PRE - q*64; if (nv > 64) nv = 64;
    u64 cur = removed, km = 0;
    #pragma unroll
    for (int jj = 0; jj < 64; ++jj) {
      if (((cur >> jj) & 1ull) == 0ull) { km |= (1ull << jj); cur |= buf[jj]; }
    }
    u64 kmw = __shfl(km, q, 64);
    if (nv < 64) kmw &= ((1ull << nv) - 1ull);
    #pragma unroll
    for (int jj = 0; jj < 64; ++jj) {
      if ((kmw >> jj) & 1ull) removed |= buf[jj];
    }
    bool mine = (kmw >> lane) & 1ull;
    int pos = kc + (int)__popcll(kmw & ((1ull << lane) - 1ull));
    if (mine && pos < POST) sel_lds[pos] = q*64 + lane;
    kc += (int)__popcll(kmw);                            // uniform across wave
    if (kc >= POST) break;                               // uniform exit
  }
  __syncthreads();
  int kcap = kc < POST ? kc : POST;
  for (int r = lane; r < POST; r += 64) {
    float4 o0 = make_float4(0.f,0.f,0.f,0.f), o1 = o0;
    if (r < kcap) {
      int i = sel_lds[r];
      const float4* p = (const float4*)(crow + ((size_t)b*CAP + i)*8);
      o0 = p[0]; o1 = p[1];
    }
    float4* q = (float4*)(out + ((size_t)b*POST + r)*8);
    q[0] = o0; q[1] = o1;
  }
}

extern "C" void kernel_launch(void* const* d_in, const int* in_sizes, int n_in,
                              void* d_out, int out_size, void* d_ws, size_t ws_size,
                              hipStream_t stream) {
  const float* obj = (const float*)d_in[0];   // (N,)
  const float* reg = (const float*)d_in[1];   // (N,7)
  const float* anc = (const float*)d_in[2];   // (N,7)
  float* out = (float*)d_out;                 // (4,1000,8)
  char* ws = (char*)d_ws;

  u32*  hist = (u32*)(ws + OFF_HIST);
  u32*  pfx  = (u32*)(ws + OFF_PFX);
  int*  cntG = (int*)(ws + OFF_CNTG);
  int*  cntE = (int*)(ws + OFF_CNTE);
  u64*  keys = (u64*)(ws + OFF_KEYS);
  float* crow = (float*)(ws + OFF_CROW);
  float* nbox = (float*)(ws + OFF_NBOX);
  u64*  mask = (u64*)(ws + OFF_MASK);

  hipMemsetAsync(ws, 0, ZERO_END, stream);   // hists + pfx + counters + keys

  k_hist16<<<NN/256, 256, 0, stream>>>(obj, hist);
  k_resolve<<<BB, 256, 0, stream>>>(hist, pfx);
  k_compact<<<NN/4096, 256, 0, stream>>>(obj, pfx, cntG, cntE, keys);
  k_rank<<<dim3(CAPR/64, BB), 64, 0, stream>>>(keys, reg, anc, crow, nbox);
  k_mask<<<dim3(NBLK, 16, BB), 256, 0, stream>>>(nbox, mask);
  k_reduce<<<BB, 64, 0, stream>>>(mask, crow, out);
}

// Round 9
// 317.613 us; speedup vs baseline: 1.2491x; 1.2491x over previous
//
#include <hip/hip_runtime.h>
#include <math.h>

typedef unsigned int u32;
typedef unsigned long long u64;

#define BB 4
#define AA 262144              // 1<<18
#define NN (BB*AA)
#define PRE 4000
#define POST 1000
#define CAP 4096               // crow/nbox row stride
#define CAPR 5632              // key slots per batch: G [0,4000) + E [4000,5632)
#define MASKW 64
#define NBLK 63                // ceil(4000/64)
#define SLICES 64              // private hist slices per batch (no atomics)

// ---- workspace layout (bytes) ----
// Only [0, ZERO_END) needs the memset (counters + keys). Hist slices and
// resolve outputs are fully overwritten every launch.
static const size_t OFF_CNTG = 0;                          // int, stride 32 ints x4
static const size_t OFF_CNTE = 512;                        // int, stride 32 ints x4
static const size_t OFF_KEYS = 1024;                       // u64[4][5632] = 176 KiB
static const size_t ZERO_END = OFF_KEYS + (size_t)BB*CAPR*8;       // 181248
static const size_t OFF_HC   = 181248;                     // u32[4][64][256] = 256 KiB
static const size_t OFF_HF   = OFF_HC + 262144;            // u32[4][64][256] = 256 KiB
static const size_t OFF_P1   = OFF_HF + 262144;            // u32[4] coarse bin C (pad 128B)
static const size_t OFF_A1   = OFF_P1 + 128;               // u32[4] count above C
static const size_t OFF_P2   = OFF_A1 + 128;               // u32[4] 16-bit threshold bin
static const size_t OFF_CROW = 706560;                             // float[4][4096][8]
static const size_t OFF_NBOX = OFF_CROW + (size_t)BB*CAP*8*4;
static const size_t OFF_MASK = OFF_NBOX + (size_t)BB*CAP*8*4;      // u64[4][64][4000] = 8 MB

// f32 sigmoid via correctly-rounded double exp (bit-exact, order == value order).
__device__ __forceinline__ u32 sigmoid_bits(float x) {
  float e = (float)exp(-(double)x);
  float s = 1.0f / (1.0f + e);
  return __float_as_uint(s);     // s in (0,1): bits > 0
}

// Monotone u32 transform of float bits (sigmoid monotone in x -> same order).
__device__ __forceinline__ u32 mono_bits(float x) {
  u32 f = __float_as_uint(x);
  return (f & 0x80000000u) ? ~f : (f | 0x80000000u);
}

// ---- coarse pass: 8-bit hist into PRIVATE per-block slices (no global atomics).
// R8 post-mortem: 1M global atomics with value-concentrated hot bins = 133 us
// of L2 serialization (WRITE_SIZE 27.5 MB). LDS counters replicated x16 kill
// the same-address LDS atomic chains (hot octave bin ~1100/block -> ~70/replica).
__global__ __launch_bounds__(256) void k_hcoarse(const float* __restrict__ obj,
                                                 u32* __restrict__ hc) {
  __shared__ u32 lh[256*16];
  int tid = threadIdx.x;
  for (int i = tid; i < 256*16; i += 256) lh[i] = 0;
  __syncthreads();
  size_t blockBase = (size_t)blockIdx.x * 4096;
  int rep = tid & 15;
  for (int k = 0; k < 16; ++k) {
    u32 tt = mono_bits(obj[blockBase + (size_t)k*256 + tid]);
    atomicAdd(&lh[(tt >> 24)*16 + rep], 1u);
  }
  __syncthreads();
  u32 s = 0;
  #pragma unroll
  for (int r = 0; r < 16; ++r) s += lh[tid*16 + r];
  hc[(size_t)blockIdx.x*256 + tid] = s;   // slice fully written, no memset needed
}

// ---- resolve1: per batch sum 64 slices, pick coarse bin C + count above ----
__global__ __launch_bounds__(256) void k_res1(const u32* __restrict__ hc,
                                              u32* __restrict__ C_out,
                                              u32* __restrict__ acc_out) {
  int b = blockIdx.x, t = threadIdx.x;
  __shared__ u32 sum[256];
  const u32* base = hc + (size_t)b*SLICES*256;
  u32 s = 0;
  for (int k = 0; k < SLICES; ++k) s += base[k*256 + t];
  sum[t] = s;
  __syncthreads();
  if (t == 0) {
    u32 acc = 0; int cs = 0;
    for (int i = 255; i >= 0; --i) {
      u32 c = sum[i];
      if (acc + c >= (u32)PRE) { cs = i; break; }
      acc += c;
    }
    C_out[b] = (u32)cs; acc_out[b] = acc;   // acc = count(coarse bin > C) <= 3999
  }
}

// ---- fine pass: hist bits[23:16] of elements whose coarse bin == C ----
// ~6K of 1M elements qualify: LDS atomic contention trivial, plain 256 bins.
__global__ __launch_bounds__(256) void k_hfine(const float* __restrict__ obj,
                                               const u32* __restrict__ C_in,
                                               u32* __restrict__ hf) {
  __shared__ u32 lh[256];
  int tid = threadIdx.x;
  lh[tid] = 0;
  __syncthreads();
  size_t blockBase = (size_t)blockIdx.x * 4096;
  int b = (int)(blockBase >> 18);
  u32 C = C_in[b];
  for (int k = 0; k < 16; ++k) {
    u32 tt = mono_bits(obj[blockBase + (size_t)k*256 + tid]);
    if ((tt >> 24) == C) atomicAdd(&lh[(tt >> 16) & 255u], 1u);
  }
  __syncthreads();
  hf[(size_t)blockIdx.x*256 + tid] = lh[tid];
}

// ---- resolve2: exact 16-bit threshold bin P = (C<<8)|fbin ----
__global__ __launch_bounds__(256) void k_res2(const u32* __restrict__ hf,
                                              const u32* __restrict__ C_in,
                                              const u32* __restrict__ acc_in,
                                              u32* __restrict__ P_out) {
  int b = blockIdx.x, t = threadIdx.x;
  __shared__ u32 sum[256];
  const u32* base = hf + (size_t)b*SLICES*256;
  u32 s = 0;
  for (int k = 0; k < SLICES; ++k) s += base[k*256 + t];
  sum[t] = s;
  __syncthreads();
  if (t == 0) {
    u32 acc = acc_in[b]; int fb = 0;
    for (int i = 255; i >= 0; --i) {
      u32 c = sum[i];
      if (acc + c >= (u32)PRE) { fb = i; break; }
      acc += c;
    }
    P_out[b] = (C_in[b] << 8) | (u32)fb;
    // count(16-bit bin > P) <= 3999 ; count(>= P) >= 4000
  }
}

// ---- compact candidates (identical semantics to R8, which passed) ----
// G (bin>P, provably <=3999) -> [0,4000); E (bins P-1,P; ~310 expected,
// cap 1632) -> [4000,5632). P-1 admission covers f32-sigmoid tie partners
// (bin width ~1e-2 in x >> tie width ~7e-7). Sigmoid computed only for
// admitted candidates. Key=(m<<32)|(AA-1-idx): desc key == top_k order;
// m>0 so zeroed padding ranks last.
__global__ __launch_bounds__(256) void k_compact(const float* __restrict__ obj,
                                                 const u32* __restrict__ pfx,
                                                 int* __restrict__ cntG,
                                                 int* __restrict__ cntE,
                                                 u64* __restrict__ keys) {
  __shared__ u64 st[2048];            // G from front, E from back
  __shared__ int nG, nE, baseG, baseE;
  int tid = threadIdx.x;
  if (tid == 0) { nG = 0; nE = 0; }
  __syncthreads();
  size_t blockBase = (size_t)blockIdx.x * 4096;
  int b = (int)(blockBase >> 18);
  u32 P = pfx[b];
  for (int k = 0; k < 16; ++k) {
    size_t g = blockBase + (size_t)k*256 + tid;
    float x = obj[g];
    u32 tb = mono_bits(x) >> 16;
    if (tb + 1u >= P) {               // admit bins P-1, P, >P
      u32 m = sigmoid_bits(x);
      u64 key = ((u64)m << 32) | (u64)(AA - 1 - (u32)(g & (AA - 1)));
      if (tb > P) { int p = atomicAdd(&nG, 1); if (p < 1536) st[p] = key; }
      else        { int p = atomicAdd(&nE, 1); if (p < 512) st[2047 - p] = key; }
    }
  }
  __syncthreads();
  int ng = nG < 1536 ? nG : 1536;
  int ne = nE < 512 ? nE : 512;
  if (tid == 0) baseG = atomicAdd(&cntG[b*32], ng);
  if (tid == 1) baseE = atomicAdd(&cntE[b*32], ne);
  __syncthreads();
  for (int i = tid; i < ng; i += 256) {
    int p = baseG + i;
    if (p < 4000) keys[(size_t)b*CAPR + p] = st[i];          // G region [0,4000)
  }
  for (int i = tid; i < ne; i += 256) {
    int p = baseE + i;
    if (p < CAPR - 4000) keys[(size_t)b*CAPR + 4000 + p] = st[2047 - i]; // E region
  }
}

// ---- rank + decode fused ----
// R8 lesson: LDS-staged wave-uniform reads stay latency/throughput-bound on
// the ds pipe. Keys are block-uniform streams -> read from GLOBAL (L2-resident
// 45KB/batch; uniform address lets the compiler use the scalar path) with
// 32-deep batches (v[32]=128 VGPR, under the 256 cap) for deep pipelining.
__global__ __launch_bounds__(64) void k_rank(const u64* __restrict__ keys,
                                             const float* __restrict__ reg,
                                             const float* __restrict__ anc,
                                             float* __restrict__ crow,
                                             float* __restrict__ nbox) {
  int b = blockIdx.y;
  int slot = blockIdx.x*64 + threadIdx.x;
  const u64* kb = keys + (size_t)b*CAPR;
  u64 myk = kb[slot];
  const ulonglong2* p2 = (const ulonglong2*)kb;
  int rank = 0;
  for (int base = 0; base < CAPR/2; base += 32) {   // 88 batches of 32x16B
    ulonglong2 v[32];
    #pragma unroll
    for (int k = 0; k < 32; ++k) v[k] = p2[base + k];
    #pragma unroll
    for (int k = 0; k < 32; ++k)
      rank += (int)(v[k].x > myk) + (int)(v[k].y > myk);
  }
  if (myk == 0 || rank >= PRE) return;    // padding or beyond top-4000
  u32 m = (u32)(myk >> 32);
  int idx = AA - 1 - (int)(myk & 0xFFFFFFFFull);
  float score = __uint_as_float(m);
  size_t g = ((size_t)b << 18) + (size_t)idx;
  const float* rg = reg + g*7;
  const float* an = anc + g*7;
  float xa=an[0], ya=an[1], za=an[2], wa=an[3], la=an[4], ha=an[5], ra=an[6];
  float dx=rg[0], dy=rg[1], dz=rg[2], dw=rg[3], dl=rg[4], dh=rg[5], dr=rg[6];
  float diag = sqrtf(wa*wa + la*la);
  float x = dx*diag + xa;
  float y = dy*diag + ya;
  float z = dz*ha + za;
  float w = expf(dw)*wa;
  float l = expf(dl)*la;
  float h = expf(dh)*ha;
  float r = dr + ra;
  float* cr = crow + ((size_t)b*CAP + rank)*8;
  cr[0]=x; cr[1]=y; cr[2]=z; cr[3]=w; cr[4]=l; cr[5]=h; cr[6]=r; cr[7]=score;
  float sx = fmaxf(w, 0.2f), sy = fmaxf(l, 0.2f), sz = fmaxf(h, 0.2f);
  float* nb = nbox + ((size_t)b*CAP + rank)*8;
  nb[0]=x - sx*0.5f; nb[1]=y - sy*0.5f; nb[2]=z;
  nb[3]=x + sx*0.5f; nb[4]=y + sy*0.5f; nb[5]=z + sz;
  nb[6]=sx*sy*sz;   nb[7]=0.f;
}

// ---- suppression bitmask, col-major mask[b][word c][row i] ----
__global__ __launch_bounds__(256) void k_mask(const float* __restrict__ nbox,
                                              u64* __restrict__ mask) {
  int c = blockIdx.x;            // word/column block 0..62
  int R = blockIdx.y;            // 256-row tile 0..15
  int b = blockIdx.z;
  if (c < R*4) return;           // tile fully below diagonal: words never read
  __shared__ float4 ca4[64], cb4[64];
  int t = threadIdx.x;
  int j0 = c*64;
  if (t < 64) {
    int j = j0 + t; int jc = j < PRE ? j : 0;
    const float4* p = (const float4*)(nbox + ((size_t)b*CAP + jc)*8);
    ca4[t] = p[0]; cb4[t] = p[1];
  }
  __syncthreads();
  int i = R*256 + t;
  if (i >= PRE) return;
  const float4* rp = (const float4*)(nbox + ((size_t)b*CAP + i)*8);
  float4 A = rp[0], Bv = rp[1];  // A = lo.xyz, hi.x ; Bv = hi.y, hi.z, vol, pad
  u64 bits = 0;
  #pragma unroll
  for (int jj = 0; jj < 64; ++jj) {
    float4 C = ca4[jj], D = cb4[jj];
    float d0 = fminf(A.w,  C.w) - fmaxf(A.x, C.x);
    float d1 = fminf(Bv.x, D.x) - fmaxf(A.y, C.y);
    float d2 = fminf(Bv.y, D.y) - fmaxf(A.z, C.z);
    float inter = fmaxf(d0, 0.f) * fmaxf(d1, 0.f) * fmaxf(d2, 0.f);
    float uni = Bv.z + D.z - inter;
    if (inter > 0.3f * uni) bits |= (1ull << jj);
  }
  int vcols = PRE - j0;                                  // >= 32 for c <= 62
  if (vcols < 64) bits &= ((1ull << vcols) - 1ull);      // clear cols >= PRE
  if (j0 <= i) {                                          // clear cols j <= i
    int d = i - j0;
    if (d >= 63) bits = 0;
    else bits &= ~((2ull << d) - 1ull);
  }
  mask[((size_t)b*MASKW + c)*PRE + i] = bits;
}

// ---- greedy NMS reduce + fused output gather: one wave per batch ----
// (R4 lesson: ONE 64-u64 register buffer only — two spill at the 256-VGPR cap.)
__global__ __launch_bounds__(64) void k_reduce(const u64* __restrict__ mask,
                                               const float* __restrict__ crow,
                                               float* __restrict__ out) {
  __shared__ int sel_lds[POST];
  int b = blockIdx.x, lane = threadIdx.x;
  const u64* col = mask + ((size_t)b*MASKW + lane)*PRE;   // this lane's word-column
  u64 removed = 0;
  int kc = 0;
  for (int q = 0; q < NBLK; ++q) {
    u64 buf[64];
    bool act = lane >= q;        // words < q of these rows were never written
    if (q < NBLK - 1) {          // rows q*64 .. q*64+63 all < PRE
      const ulonglong2* p = (const ulonglong2*)(col + q*64);
      #pragma unroll
      for (int jj = 0; jj < 32; ++jj) {
        ulonglong2 v; v.x = 0; v.y = 0;
        if (act) v = p[jj];
        buf[2*jj] = v.x; buf[2*jj+1] = v.y;
      }
    } else {                     // last block: guard rows >= PRE
      #pragma unroll
      for (int jj = 0; jj < 64; ++jj) {
        int row = q*64 + jj;
        u64 v = 0;
        if (act && row < PRE) v = col[row];
        buf[jj] = v;
      }
    }
    int nv = PRE - q*64; if (nv > 64) nv = 64;
    u64 cur = removed, km = 0;
    #pragma unroll
    for (int jj = 0; jj < 64; ++jj) {
      if (((cur >> jj) & 1ull) == 0ull) { km |= (1ull << jj); cur |= buf[jj]; }
    }
    u64 kmw = __shfl(km, q, 64);
    if (nv < 64) kmw &= ((1ull << nv) - 1ull);
    #pragma unroll
    for (int jj = 0; jj < 64; ++jj) {
      if ((kmw >> jj) & 1ull) removed |= buf[jj];
    }
    bool mine = (kmw >> lane) & 1ull;
    int pos = kc + (int)__popcll(kmw & ((1ull << lane) - 1ull));
    if (mine && pos < POST) sel_lds[pos] = q*64 + lane;
    kc += (int)__popcll(kmw);                            // uniform across wave
    if (kc >= POST) break;                               // uniform exit
  }
  __syncthreads();
  int kcap = kc < POST ? kc : POST;
  for (int r = lane; r < POST; r += 64) {
    float4 o0 = make_float4(0.f,0.f,0.f,0.f), o1 = o0;
    if (r < kcap) {
      int i = sel_lds[r];
      const float4* p = (const float4*)(crow + ((size_t)b*CAP + i)*8);
      o0 = p[0]; o1 = p[1];
    }
    float4* q = (float4*)(out + ((size_t)b*POST + r)*8);
    q[0] = o0; q[1] = o1;
  }
}

extern "C" void kernel_launch(void* const* d_in, const int* in_sizes, int n_in,
                              void* d_out, int out_size, void* d_ws, size_t ws_size,
                              hipStream_t stream) {
  const float* obj = (const float*)d_in[0];   // (N,)
  const float* reg = (const float*)d_in[1];   // (N,7)
  const float* anc = (const float*)d_in[2];   // (N,7)
  float* out = (float*)d_out;                 // (4,1000,8)
  char* ws = (char*)d_ws;

  int*  cntG = (int*)(ws + OFF_CNTG);
  int*  cntE = (int*)(ws + OFF_CNTE);
  u64*  keys = (u64*)(ws + OFF_KEYS);
  u32*  hc   = (u32*)(ws + OFF_HC);
  u32*  hf   = (u32*)(ws + OFF_HF);
  u32*  P1   = (u32*)(ws + OFF_P1);
  u32*  A1   = (u32*)(ws + OFF_A1);
  u32*  P2   = (u32*)(ws + OFF_P2);
  float* crow = (float*)(ws + OFF_CROW);
  float* nbox = (float*)(ws + OFF_NBOX);
  u64*  mask = (u64*)(ws + OFF_MASK);

  hipMemsetAsync(ws, 0, ZERO_END, stream);   // counters + keys only

  k_hcoarse<<<NN/4096, 256, 0, stream>>>(obj, hc);
  k_res1<<<BB, 256, 0, stream>>>(hc, P1, A1);
  k_hfine<<<NN/4096, 256, 0, stream>>>(obj, P1, hf);
  k_res2<<<BB, 256, 0, stream>>>(hf, P1, A1, P2);
  k_compact<<<NN/4096, 256, 0, stream>>>(obj, P2, cntG, cntE, keys);
  k_rank<<<dim3(CAPR/64, BB), 64, 0, stream>>>(keys, reg, anc, crow, nbox);
  k_mask<<<dim3(NBLK, 16, BB), 256, 0, stream>>>(nbox, mask);
  k_reduce<<<BB, 64, 0, stream>>>(mask, crow, out);
}

// Round 10
// 227.074 us; speedup vs baseline: 1.7472x; 1.3987x over previous
//
#include <hip/hip_runtime.h>
#include <math.h>

typedef unsigned int u32;
typedef unsigned long long u64;

#define BB 4
#define AA 262144              // 1<<18
#define NN (BB*AA)
#define PRE 4000
#define POST 1000
#define CAP 4096               // crow/nbox row stride
#define CAPR 5632              // key slots per batch: G [0,4000) + E [4000,5632)
#define MASKW 64
#define NBLK 63                // ceil(4000/64)
#define SLICES 64              // private hist slices per batch (no atomics)
#define RSLICE 8               // rank j-slices (occupancy for k_rankp)

// ---- workspace layout (bytes) ----
// [0, ZERO_END) cleared by ONE memset: counters + keys + rank partials.
static const size_t OFF_CNTG = 0;                          // int, stride 32 ints x4
static const size_t OFF_CNTE = 512;                        // int, stride 32 ints x4
static const size_t OFF_KEYS = 1024;                       // u64[4][5632] = 176 KiB
static const size_t OFF_RANK = OFF_KEYS + (size_t)BB*CAPR*8;       // u32[4][5632]
static const size_t ZERO_END = OFF_RANK + (size_t)BB*CAPR*4;       // 271360
static const size_t OFF_HC   = ZERO_END;                   // u32[4][64][256] = 256 KiB
static const size_t OFF_HF   = OFF_HC + 262144;            // u32[4][64][256] = 256 KiB
static const size_t OFF_P1   = OFF_HF + 262144;            // u32[4] coarse bin C (pad)
static const size_t OFF_A1   = OFF_P1 + 128;               // u32[4] count above C
static const size_t OFF_P2   = OFF_A1 + 128;               // u32[4] 16-bit threshold
static const size_t OFF_CROW = OFF_P2 + 128;                       // float[4][4096][8]
static const size_t OFF_NBOX = OFF_CROW + (size_t)BB*CAP*8*4;
static const size_t OFF_MASK = OFF_NBOX + (size_t)BB*CAP*8*4;      // u64[4][64][4000] = 8 MB

// f32 sigmoid via correctly-rounded double exp (bit-exact, order == value order).
__device__ __forceinline__ u32 sigmoid_bits(float x) {
  float e = (float)exp(-(double)x);
  float s = 1.0f / (1.0f + e);
  return __float_as_uint(s);     // s in (0,1): bits > 0
}

// Monotone u32 transform of float bits (sigmoid monotone in x -> same order).
__device__ __forceinline__ u32 mono_bits(float x) {
  u32 f = __float_as_uint(x);
  return (f & 0x80000000u) ? ~f : (f | 0x80000000u);
}

// ---- coarse pass: 8-bit hist into PRIVATE per-block slices (no global atomics).
__global__ __launch_bounds__(256) void k_hcoarse(const float* __restrict__ obj,
                                                 u32* __restrict__ hc) {
  __shared__ u32 lh[256*16];
  int tid = threadIdx.x;
  for (int i = tid; i < 256*16; i += 256) lh[i] = 0;
  __syncthreads();
  size_t blockBase = (size_t)blockIdx.x * 4096;
  int rep = tid & 15;
  for (int k = 0; k < 16; ++k) {
    u32 tt = mono_bits(obj[blockBase + (size_t)k*256 + tid]);
    atomicAdd(&lh[(tt >> 24)*16 + rep], 1u);
  }
  __syncthreads();
  u32 s = 0;
  #pragma unroll
  for (int r = 0; r < 16; ++r) s += lh[tid*16 + r];
  hc[(size_t)blockIdx.x*256 + tid] = s;   // slice fully written, no memset needed
}

// ---- resolve1: per batch sum 64 slices, pick coarse bin C + count above ----
__global__ __launch_bounds__(256) void k_res1(const u32* __restrict__ hc,
                                              u32* __restrict__ C_out,
                                              u32* __restrict__ acc_out) {
  int b = blockIdx.x, t = threadIdx.x;
  __shared__ u32 sum[256];
  const u32* base = hc + (size_t)b*SLICES*256;
  u32 s = 0;
  for (int k = 0; k < SLICES; ++k) s += base[k*256 + t];
  sum[t] = s;
  __syncthreads();
  if (t == 0) {
    u32 acc = 0; int cs = 0;
    for (int i = 255; i >= 0; --i) {
      u32 c = sum[i];
      if (acc + c >= (u32)PRE) { cs = i; break; }
      acc += c;
    }
    C_out[b] = (u32)cs; acc_out[b] = acc;   // acc = count(coarse bin > C) <= 3999
  }
}

// ---- fine pass: hist bits[23:16] of elements whose coarse bin == C ----
__global__ __launch_bounds__(256) void k_hfine(const float* __restrict__ obj,
                                               const u32* __restrict__ C_in,
                                               u32* __restrict__ hf) {
  __shared__ u32 lh[256];
  int tid = threadIdx.x;
  lh[tid] = 0;
  __syncthreads();
  size_t blockBase = (size_t)blockIdx.x * 4096;
  int b = (int)(blockBase >> 18);
  u32 C = C_in[b];
  for (int k = 0; k < 16; ++k) {
    u32 tt = mono_bits(obj[blockBase + (size_t)k*256 + tid]);
    if ((tt >> 24) == C) atomicAdd(&lh[(tt >> 16) & 255u], 1u);
  }
  __syncthreads();
  hf[(size_t)blockIdx.x*256 + tid] = lh[tid];
}

// ---- resolve2: exact 16-bit threshold bin P = (C<<8)|fbin ----
__global__ __launch_bounds__(256) void k_res2(const u32* __restrict__ hf,
                                              const u32* __restrict__ C_in,
                                              const u32* __restrict__ acc_in,
                                              u32* __restrict__ P_out) {
  int b = blockIdx.x, t = threadIdx.x;
  __shared__ u32 sum[256];
  const u32* base = hf + (size_t)b*SLICES*256;
  u32 s = 0;
  for (int k = 0; k < SLICES; ++k) s += base[k*256 + t];
  sum[t] = s;
  __syncthreads();
  if (t == 0) {
    u32 acc = acc_in[b]; int fb = 0;
    for (int i = 255; i >= 0; --i) {
      u32 c = sum[i];
      if (acc + c >= (u32)PRE) { fb = i; break; }
      acc += c;
    }
    P_out[b] = (C_in[b] << 8) | (u32)fb;
  }
}

// ---- compact candidates (R8 semantics, passed) ----
// G (bin>P, provably <=3999) -> [0,4000); E (bins P-1,P) -> [4000,5632).
__global__ __launch_bounds__(256) void k_compact(const float* __restrict__ obj,
                                                 const u32* __restrict__ pfx,
                                                 int* __restrict__ cntG,
                                                 int* __restrict__ cntE,
                                                 u64* __restrict__ keys) {
  __shared__ u64 st[2048];            // G from front, E from back
  __shared__ int nG, nE, baseG, baseE;
  int tid = threadIdx.x;
  if (tid == 0) { nG = 0; nE = 0; }
  __syncthreads();
  size_t blockBase = (size_t)blockIdx.x * 4096;
  int b = (int)(blockBase >> 18);
  u32 P = pfx[b];
  for (int k = 0; k < 16; ++k) {
    size_t g = blockBase + (size_t)k*256 + tid;
    float x = obj[g];
    u32 tb = mono_bits(x) >> 16;
    if (tb + 1u >= P) {               // admit bins P-1, P, >P
      u32 m = sigmoid_bits(x);
      u64 key = ((u64)m << 32) | (u64)(AA - 1 - (u32)(g & (AA - 1)));
      if (tb > P) { int p = atomicAdd(&nG, 1); if (p < 1536) st[p] = key; }
      else        { int p = atomicAdd(&nE, 1); if (p < 512) st[2047 - p] = key; }
    }
  }
  __syncthreads();
  int ng = nG < 1536 ? nG : 1536;
  int ne = nE < 512 ? nE : 512;
  if (tid == 0) baseG = atomicAdd(&cntG[b*32], ng);
  if (tid == 1) baseE = atomicAdd(&cntE[b*32], ne);
  __syncthreads();
  for (int i = tid; i < ng; i += 256) {
    int p = baseG + i;
    if (p < 4000) keys[(size_t)b*CAPR + p] = st[i];          // G region [0,4000)
  }
  for (int i = tid; i < ne; i += 256) {
    int p = baseE + i;
    if (p < CAPR - 4000) keys[(size_t)b*CAPR + 4000 + p] = st[2047 - i]; // E region
  }
}

// ---- partial rank: sliced for occupancy ----
// R6/R8/R9 post-mortem: every 1-wave-per-CU variant of ranking was latency
// bound regardless of load path (LDS broadcast / batched LDS / scalar SMEM).
// Fix the STRUCTURE: 88 tiles x 8 slices x 4 batches = 2816 single-wave
// blocks (~11 waves/CU). Each block: 64 keys vs a 704-key slice; ONE
// non-returning atomicAdd per key (8 writers per counter, 22K counters).
__global__ __launch_bounds__(64) void k_rankp(const u64* __restrict__ keys,
                                              u32* __restrict__ rank) {
  int b = blockIdx.z;
  int slot = blockIdx.x*64 + threadIdx.x;
  const u64* kb = keys + (size_t)b*CAPR;
  u64 myk = kb[slot];
  const ulonglong2* p2 = (const ulonglong2*)(kb + blockIdx.y*(CAPR/RSLICE));
  int r = 0;
  for (int base = 0; base < CAPR/(2*RSLICE); base += 16) {   // 22 batches of 16
    ulonglong2 v[16];
    #pragma unroll
    for (int k = 0; k < 16; ++k) v[k] = p2[base + k];
    #pragma unroll
    for (int k = 0; k < 16; ++k)
      r += (int)(v[k].x > myk) + (int)(v[k].y > myk);
  }
  if (r) atomicAdd(&rank[b*CAPR + slot], (u32)r);
}

// ---- decode top-4000 by final rank (data-parallel, full occupancy) ----
__global__ __launch_bounds__(256) void k_decode(const u64* __restrict__ keys,
                                                const u32* __restrict__ rank,
                                                const float* __restrict__ reg,
                                                const float* __restrict__ anc,
                                                float* __restrict__ crow,
                                                float* __restrict__ nbox) {
  int t = blockIdx.x*256 + threadIdx.x;        // over BB*CAPR
  int b = t / CAPR, slot = t - b*CAPR;
  u64 myk = keys[(size_t)b*CAPR + slot];
  int rk = (int)rank[b*CAPR + slot];
  if (myk == 0 || rk >= PRE) return;           // padding or beyond top-4000
  u32 m = (u32)(myk >> 32);
  int idx = AA - 1 - (int)(myk & 0xFFFFFFFFull);
  float score = __uint_as_float(m);
  size_t g = ((size_t)b << 18) + (size_t)idx;
  const float* rg = reg + g*7;
  const float* an = anc + g*7;
  float xa=an[0], ya=an[1], za=an[2], wa=an[3], la=an[4], ha=an[5], ra=an[6];
  float dx=rg[0], dy=rg[1], dz=rg[2], dw=rg[3], dl=rg[4], dh=rg[5], dr=rg[6];
  float diag = sqrtf(wa*wa + la*la);
  float x = dx*diag + xa;
  float y = dy*diag + ya;
  float z = dz*ha + za;
  float w = expf(dw)*wa;
  float l = expf(dl)*la;
  float h = expf(dh)*ha;
  float r = dr + ra;
  float* cr = crow + ((size_t)b*CAP + rk)*8;
  cr[0]=x; cr[1]=y; cr[2]=z; cr[3]=w; cr[4]=l; cr[5]=h; cr[6]=r; cr[7]=score;
  float sx = fmaxf(w, 0.2f), sy = fmaxf(l, 0.2f), sz = fmaxf(h, 0.2f);
  float* nb = nbox + ((size_t)b*CAP + rk)*8;
  nb[0]=x - sx*0.5f; nb[1]=y - sy*0.5f; nb[2]=z;
  nb[3]=x + sx*0.5f; nb[4]=y + sy*0.5f; nb[5]=z + sz;
  nb[6]=sx*sy*sz;   nb[7]=0.f;
}

// ---- suppression bitmask, col-major mask[b][word c][row i] ----
__global__ __launch_bounds__(256) void k_mask(const float* __restrict__ nbox,
                                              u64* __restrict__ mask) {
  int c = blockIdx.x;            // word/column block 0..62
  int R = blockIdx.y;            // 256-row tile 0..15
  int b = blockIdx.z;
  if (c < R*4) return;           // tile fully below diagonal: words never read
  __shared__ float4 ca4[64], cb4[64];
  int t = threadIdx.x;
  int j0 = c*64;
  if (t < 64) {
    int j = j0 + t; int jc = j < PRE ? j : 0;
    const float4* p = (const float4*)(nbox + ((size_t)b*CAP + jc)*8);
    ca4[t] = p[0]; cb4[t] = p[1];
  }
  __syncthreads();
  int i = R*256 + t;
  if (i >= PRE) return;
  const float4* rp = (const float4*)(nbox + ((size_t)b*CAP + i)*8);
  float4 A = rp[0], Bv = rp[1];  // A = lo.xyz, hi.x ; Bv = hi.y, hi.z, vol, pad
  u64 bits = 0;
  #pragma unroll
  for (int jj = 0; jj < 64; ++jj) {
    float4 C = ca4[jj], D = cb4[jj];
    float d0 = fminf(A.w,  C.w) - fmaxf(A.x, C.x);
    float d1 = fminf(Bv.x, D.x) - fmaxf(A.y, C.y);
    float d2 = fminf(Bv.y, D.y) - fmaxf(A.z, C.z);
    float inter = fmaxf(d0, 0.f) * fmaxf(d1, 0.f) * fmaxf(d2, 0.f);
    float uni = Bv.z + D.z - inter;
    if (inter > 0.3f * uni) bits |= (1ull << jj);
  }
  int vcols = PRE - j0;                                  // >= 32 for c <= 62
  if (vcols < 64) bits &= ((1ull << vcols) - 1ull);      // clear cols >= PRE
  if (j0 <= i) {                                          // clear cols j <= i
    int d = i - j0;
    if (d >= 63) bits = 0;
    else bits &= ~((2ull << d) - 1ull);
  }
  mask[((size_t)b*MASKW + c)*PRE + i] = bits;
}

// ---- greedy NMS reduce + fused output gather: one wave per batch ----
// (R4 lesson: ONE 64-u64 register buffer only — two spill at the 256-VGPR cap.)
__global__ __launch_bounds__(64) void k_reduce(const u64* __restrict__ mask,
                                               const float* __restrict__ crow,
                                               float* __restrict__ out) {
  __shared__ int sel_lds[POST];
  int b = blockIdx.x, lane = threadIdx.x;
  const u64* col = mask + ((size_t)b*MASKW + lane)*PRE;   // this lane's word-column
  u64 removed = 0;
  int kc = 0;
  for (int q = 0; q < NBLK; ++q) {
    u64 buf[64];
    bool act = lane >= q;        // words < q of these rows were never written
    if (q < NBLK - 1) {          // rows q*64 .. q*64+63 all < PRE
      const ulonglong2* p = (const ulonglong2*)(col + q*64);
      #pragma unroll
      for (int jj = 0; jj < 32; ++jj) {
        ulonglong2 v; v.x = 0; v.y = 0;
        if (act) v = p[jj];
        buf[2*jj] = v.x; buf[2*jj+1] = v.y;
      }
    } else {                     // last block: guard rows >= PRE
      #pragma unroll
      for (int jj = 0; jj < 64; ++jj) {
        int row = q*64 + jj;
        u64 v = 0;
        if (act && row < PRE) v = col[row];
        buf[jj] = v;
      }
    }
    int nv = PRE - q*64; if (nv > 64) nv = 64;
    u64 cur = removed, km = 0;
    #pragma unroll
    for (int jj = 0; jj < 64; ++jj) {
      if (((cur >> jj) & 1ull) == 0ull) { km |= (1ull << jj); cur |= buf[jj]; }
    }
    u64 kmw = __shfl(km, q, 64);
    if (nv < 64) kmw &= ((1ull << nv) - 1ull);
    #pragma unroll
    for (int jj = 0; jj < 64; ++jj) {
      if ((kmw >> jj) & 1ull) removed |= buf[jj];
    }
    bool mine = (kmw >> lane) & 1ull;
    int pos = kc + (int)__popcll(kmw & ((1ull << lane) - 1ull));
    if (mine && pos < POST) sel_lds[pos] = q*64 + lane;
    kc += (int)__popcll(kmw);                            // uniform across wave
    if (kc >= POST) break;                               // uniform exit
  }
  __syncthreads();
  int kcap = kc < POST ? kc : POST;
  for (int r = lane; r < POST; r += 64) {
    float4 o0 = make_float4(0.f,0.f,0.f,0.f), o1 = o0;
    if (r < kcap) {
      int i = sel_lds[r];
      const float4* p = (const float4*)(crow + ((size_t)b*CAP + i)*8);
      o0 = p[0]; o1 = p[1];
    }
    float4* q = (float4*)(out + ((size_t)b*POST + r)*8);
    q[0] = o0; q[1] = o1;
  }
}

extern "C" void kernel_launch(void* const* d_in, const int* in_sizes, int n_in,
                              void* d_out, int out_size, void* d_ws, size_t ws_size,
                              hipStream_t stream) {
  const float* obj = (const float*)d_in[0];   // (N,)
  const float* reg = (const float*)d_in[1];   // (N,7)
  const float* anc = (const float*)d_in[2];   // (N,7)
  float* out = (float*)d_out;                 // (4,1000,8)
  char* ws = (char*)d_ws;

  int*  cntG = (int*)(ws + OFF_CNTG);
  int*  cntE = (int*)(ws + OFF_CNTE);
  u64*  keys = (u64*)(ws + OFF_KEYS);
  u32*  rank = (u32*)(ws + OFF_RANK);
  u32*  hc   = (u32*)(ws + OFF_HC);
  u32*  hf   = (u32*)(ws + OFF_HF);
  u32*  P1   = (u32*)(ws + OFF_P1);
  u32*  A1   = (u32*)(ws + OFF_A1);
  u32*  P2   = (u32*)(ws + OFF_P2);
  float* crow = (float*)(ws + OFF_CROW);
  float* nbox = (float*)(ws + OFF_NBOX);
  u64*  mask = (u64*)(ws + OFF_MASK);

  hipMemsetAsync(ws, 0, ZERO_END, stream);   // counters + keys + rank

  k_hcoarse<<<NN/4096, 256, 0, stream>>>(obj, hc);
  k_res1<<<BB, 256, 0, stream>>>(hc, P1, A1);
  k_hfine<<<NN/4096, 256, 0, stream>>>(obj, P1, hf);
  k_res2<<<BB, 256, 0, stream>>>(hf, P1, A1, P2);
  k_compact<<<NN/4096, 256, 0, stream>>>(obj, P2, cntG, cntE, keys);
  k_rankp<<<dim3(CAPR/64, RSLICE, BB), 64, 0, stream>>>(keys, rank);
  k_decode<<<(BB*CAPR)/256, 256, 0, stream>>>(keys, rank, reg, anc, crow, nbox);
  k_mask<<<dim3(NBLK, 16, BB), 256, 0, stream>>>(nbox, mask);
  k_reduce<<<BB, 64, 0, stream>>>(mask, crow, out);
}

// Round 12
// 220.960 us; speedup vs baseline: 1.7955x; 1.0277x over previous
//
#include <hip/hip_runtime.h>
#include <math.h>

typedef unsigned int u32;
typedef unsigned long long u64;

#define BB 4
#define AA 262144              // 1<<18
#define NN (BB*AA)
#define PRE 4000
#define POST 1000
#define CAP 4096               // crow/nbox row stride
#define CAPR 5632              // key slots per batch: G [0,4000) + E [4000,5632)
#define MASKW 64
#define NBLK 63                // ceil(4000/64) mask word-blocks
#define NCHUNK 125             // 4000 / 32 exactly (reduce chunks)
#define SLICES 64              // private hist slices per batch (no atomics)
#define RSLICE 8               // rank j-slices (occupancy for k_rankp)

// ---- workspace layout (bytes) ----
// [0, ZERO_END) cleared by ONE memset: counters + keys + rank partials.
static const size_t OFF_CNTG = 0;                          // int, stride 32 ints x4
static const size_t OFF_CNTE = 512;                        // int, stride 32 ints x4
static const size_t OFF_KEYS = 1024;                       // u64[4][5632] = 176 KiB
static const size_t OFF_RANK = OFF_KEYS + (size_t)BB*CAPR*8;       // u32[4][5632]
static const size_t ZERO_END = OFF_RANK + (size_t)BB*CAPR*4;       // 271360
static const size_t OFF_HC   = ZERO_END;                   // u32[4][64][256] = 256 KiB
static const size_t OFF_HF   = OFF_HC + 262144;            // u32[4][64][256] = 256 KiB
static const size_t OFF_P1   = OFF_HF + 262144;            // u32[4] coarse bin C (pad)
static const size_t OFF_A1   = OFF_P1 + 128;               // u32[4] count above C
static const size_t OFF_P2   = OFF_A1 + 128;               // u32[4] 16-bit threshold
static const size_t OFF_CROW = OFF_P2 + 128;                       // float[4][4096][8]
static const size_t OFF_NBOX = OFF_CROW + (size_t)BB*CAP*8*4;
static const size_t OFF_MASK = OFF_NBOX + (size_t)BB*CAP*8*4;      // u64[4][64][4000] = 8 MB

// f32 sigmoid via correctly-rounded double exp (bit-exact, order == value order).
__device__ __forceinline__ u32 sigmoid_bits(float x) {
  float e = (float)exp(-(double)x);
  float s = 1.0f / (1.0f + e);
  return __float_as_uint(s);     // s in (0,1): bits > 0
}

// Monotone u32 transform of float bits (sigmoid monotone in x -> same order).
__device__ __forceinline__ u32 mono_bits(float x) {
  u32 f = __float_as_uint(x);
  return (f & 0x80000000u) ? ~f : (f | 0x80000000u);
}

// ---- coarse pass: 8-bit hist into PRIVATE per-block slices (no global atomics).
__global__ __launch_bounds__(256) void k_hcoarse(const float* __restrict__ obj,
                                                 u32* __restrict__ hc) {
  __shared__ u32 lh[256*16];
  int tid = threadIdx.x;
  for (int i = tid; i < 256*16; i += 256) lh[i] = 0;
  __syncthreads();
  size_t blockBase = (size_t)blockIdx.x * 4096;
  int rep = tid & 15;
  for (int k = 0; k < 16; ++k) {
    u32 tt = mono_bits(obj[blockBase + (size_t)k*256 + tid]);
    atomicAdd(&lh[(tt >> 24)*16 + rep], 1u);
  }
  __syncthreads();
  u32 s = 0;
  #pragma unroll
  for (int r = 0; r < 16; ++r) s += lh[tid*16 + r];
  hc[(size_t)blockIdx.x*256 + tid] = s;   // slice fully written, no memset needed
}

// ---- resolve1: per batch sum 64 slices, pick coarse bin C + count above ----
__global__ __launch_bounds__(256) void k_res1(const u32* __restrict__ hc,
                                              u32* __restrict__ C_out,
                                              u32* __restrict__ acc_out) {
  int b = blockIdx.x, t = threadIdx.x;
  __shared__ u32 sum[256];
  const u32* base = hc + (size_t)b*SLICES*256;
  u32 s = 0;
  for (int k = 0; k < SLICES; ++k) s += base[k*256 + t];
  sum[t] = s;
  __syncthreads();
  if (t == 0) {
    u32 acc = 0; int cs = 0;
    for (int i = 255; i >= 0; --i) {
      u32 c = sum[i];
      if (acc + c >= (u32)PRE) { cs = i; break; }
      acc += c;
    }
    C_out[b] = (u32)cs; acc_out[b] = acc;   // acc = count(coarse bin > C) <= 3999
  }
}

// ---- fine pass: hist bits[23:16] of elements whose coarse bin == C ----
__global__ __launch_bounds__(256) void k_hfine(const float* __restrict__ obj,
                                               const u32* __restrict__ C_in,
                                               u32* __restrict__ hf) {
  __shared__ u32 lh[256];
  int tid = threadIdx.x;
  lh[tid] = 0;
  __syncthreads();
  size_t blockBase = (size_t)blockIdx.x * 4096;
  int b = (int)(blockBase >> 18);
  u32 C = C_in[b];
  for (int k = 0; k < 16; ++k) {
    u32 tt = mono_bits(obj[blockBase + (size_t)k*256 + tid]);
    if ((tt >> 24) == C) atomicAdd(&lh[(tt >> 16) & 255u], 1u);
  }
  __syncthreads();
  hf[(size_t)blockIdx.x*256 + tid] = lh[tid];
}

// ---- resolve2: exact 16-bit threshold bin P = (C<<8)|fbin ----
__global__ __launch_bounds__(256) void k_res2(const u32* __restrict__ hf,
                                              const u32* __restrict__ C_in,
                                              const u32* __restrict__ acc_in,
                                              u32* __restrict__ P_out) {
  int b = blockIdx.x, t = threadIdx.x;
  __shared__ u32 sum[256];
  const u32* base = hf + (size_t)b*SLICES*256;
  u32 s = 0;
  for (int k = 0; k < SLICES; ++k) s += base[k*256 + t];
  sum[t] = s;
  __syncthreads();
  if (t == 0) {
    u32 acc = acc_in[b]; int fb = 0;
    for (int i = 255; i >= 0; --i) {
      u32 c = sum[i];
      if (acc + c >= (u32)PRE) { fb = i; break; }
      acc += c;
    }
    P_out[b] = (C_in[b] << 8) | (u32)fb;
  }
}

// ---- compact candidates (R8 semantics, passed) ----
// G (bin>P, provably <=3999) -> [0,4000); E (bins P-1,P) -> [4000,5632).
__global__ __launch_bounds__(256) void k_compact(const float* __restrict__ obj,
                                                 const u32* __restrict__ pfx,
                                                 int* __restrict__ cntG,
                                                 int* __restrict__ cntE,
                                                 u64* __restrict__ keys) {
  __shared__ u64 st[2048];            // G from front, E from back
  __shared__ int nG, nE, baseG, baseE;
  int tid = threadIdx.x;
  if (tid == 0) { nG = 0; nE = 0; }
  __syncthreads();
  size_t blockBase = (size_t)blockIdx.x * 4096;
  int b = (int)(blockBase >> 18);
  u32 P = pfx[b];
  for (int k = 0; k < 16; ++k) {
    size_t g = blockBase + (size_t)k*256 + tid;
    float x = obj[g];
    u32 tb = mono_bits(x) >> 16;
    if (tb + 1u >= P) {               // admit bins P-1, P, >P
      u32 m = sigmoid_bits(x);
      u64 key = ((u64)m << 32) | (u64)(AA - 1 - (u32)(g & (AA - 1)));
      if (tb > P) { int p = atomicAdd(&nG, 1); if (p < 1536) st[p] = key; }
      else        { int p = atomicAdd(&nE, 1); if (p < 512) st[2047 - p] = key; }
    }
  }
  __syncthreads();
  int ng = nG < 1536 ? nG : 1536;
  int ne = nE < 512 ? nE : 512;
  if (tid == 0) baseG = atomicAdd(&cntG[b*32], ng);
  if (tid == 1) baseE = atomicAdd(&cntE[b*32], ne);
  __syncthreads();
  for (int i = tid; i < ng; i += 256) {
    int p = baseG + i;
    if (p < 4000) keys[(size_t)b*CAPR + p] = st[i];          // G region [0,4000)
  }
  for (int i = tid; i < ne; i += 256) {
    int p = baseE + i;
    if (p < CAPR - 4000) keys[(size_t)b*CAPR + 4000 + p] = st[2047 - i]; // E region
  }
}

// ---- partial rank: sliced for occupancy (R10 win: ~11 waves/CU) ----
__global__ __launch_bounds__(64) void k_rankp(const u64* __restrict__ keys,
                                              u32* __restrict__ rank) {
  int b = blockIdx.z;
  int slot = blockIdx.x*64 + threadIdx.x;
  const u64* kb = keys + (size_t)b*CAPR;
  u64 myk = kb[slot];
  const ulonglong2* p2 = (const ulonglong2*)(kb + blockIdx.y*(CAPR/RSLICE));
  int r = 0;
  for (int base = 0; base < CAPR/(2*RSLICE); base += 16) {   // 22 batches of 16
    ulonglong2 v[16];
    #pragma unroll
    for (int k = 0; k < 16; ++k) v[k] = p2[base + k];
    #pragma unroll
    for (int k = 0; k < 16; ++k)
      r += (int)(v[k].x > myk) + (int)(v[k].y > myk);
  }
  if (r) atomicAdd(&rank[b*CAPR + slot], (u32)r);
}

// ---- decode top-4000 by final rank (data-parallel, full occupancy) ----
__global__ __launch_bounds__(256) void k_decode(const u64* __restrict__ keys,
                                                const u32* __restrict__ rank,
                                                const float* __restrict__ reg,
                                                const float* __restrict__ anc,
                                                float* __restrict__ crow,
                                                float* __restrict__ nbox) {
  int t = blockIdx.x*256 + threadIdx.x;        // over BB*CAPR
  int b = t / CAPR, slot = t - b*CAPR;
  u64 myk = keys[(size_t)b*CAPR + slot];
  int rk = (int)rank[b*CAPR + slot];
  if (myk == 0 || rk >= PRE) return;           // padding or beyond top-4000
  u32 m = (u32)(myk >> 32);
  int idx = AA - 1 - (int)(myk & 0xFFFFFFFFull);
  float score = __uint_as_float(m);
  size_t g = ((size_t)b << 18) + (size_t)idx;
  const float* rg = reg + g*7;
  const float* an = anc + g*7;
  float xa=an[0], ya=an[1], za=an[2], wa=an[3], la=an[4], ha=an[5], ra=an[6];
  float dx=rg[0], dy=rg[1], dz=rg[2], dw=rg[3], dl=rg[4], dh=rg[5], dr=rg[6];
  float diag = sqrtf(wa*wa + la*la);
  float x = dx*diag + xa;
  float y = dy*diag + ya;
  float z = dz*ha + za;
  float w = expf(dw)*wa;
  float l = expf(dl)*la;
  float h = expf(dh)*ha;
  float r = dr + ra;
  float* cr = crow + ((size_t)b*CAP + rk)*8;
  cr[0]=x; cr[1]=y; cr[2]=z; cr[3]=w; cr[4]=l; cr[5]=h; cr[6]=r; cr[7]=score;
  float sx = fmaxf(w, 0.2f), sy = fmaxf(l, 0.2f), sz = fmaxf(h, 0.2f);
  float* nb = nbox + ((size_t)b*CAP + rk)*8;
  nb[0]=x - sx*0.5f; nb[1]=y - sy*0.5f; nb[2]=z;
  nb[3]=x + sx*0.5f; nb[4]=y + sy*0.5f; nb[5]=z + sz;
  nb[6]=sx*sy*sz;   nb[7]=0.f;
}

// ---- suppression bitmask, col-major mask[b][word c][row i] ----
__global__ __launch_bounds__(256) void k_mask(const float* __restrict__ nbox,
                                              u64* __restrict__ mask) {
  int c = blockIdx.x;            // word/column block 0..62
  int R = blockIdx.y;            // 256-row tile 0..15
  int b = blockIdx.z;
  if (c < R*4) return;           // tile fully below diagonal: words never read
  __shared__ float4 ca4[64], cb4[64];
  int t = threadIdx.x;
  int j0 = c*64;
  if (t < 64) {
    int j = j0 + t; int jc = j < PRE ? j : 0;
    const float4* p = (const float4*)(nbox + ((size_t)b*CAP + jc)*8);
    ca4[t] = p[0]; cb4[t] = p[1];
  }
  __syncthreads();
  int i = R*256 + t;
  if (i >= PRE) return;
  const float4* rp = (const float4*)(nbox + ((size_t)b*CAP + i)*8);
  float4 A = rp[0], Bv = rp[1];  // A = lo.xyz, hi.x ; Bv = hi.y, hi.z, vol, pad
  u64 bits = 0;
  #pragma unroll
  for (int jj = 0; jj < 64; ++jj) {
    float4 C = ca4[jj], D = cb4[jj];
    float d0 = fminf(A.w,  C.w) - fmaxf(A.x, C.x);
    float d1 = fminf(Bv.x, D.x) - fmaxf(A.y, C.y);
    float d2 = fminf(Bv.y, D.y) - fmaxf(A.z, C.z);
    float inter = fmaxf(d0, 0.f) * fmaxf(d1, 0.f) * fmaxf(d2, 0.f);
    float uni = Bv.z + D.z - inter;
    if (inter > 0.3f * uni) bits |= (1ull << jj);
  }
  int vcols = PRE - j0;                                  // >= 32 for c <= 62
  if (vcols < 64) bits &= ((1ull << vcols) - 1ull);      // clear cols >= PRE
  if (j0 <= i) {                                          // clear cols j <= i
    int d = i - j0;
    if (d >= 63) bits = 0;
    else bits &= ~((2ull << d) - 1ull);
  }
  mask[((size_t)b*MASKW + c)*PRE + i] = bits;
}

// ---- greedy NMS reduce, 32-row chunked DOUBLE-BUFFER + fused output ----
// R10 post-mortem: single 64-row buffer serializes load-wait (~400-900 cyc,
// remote-XCD dirty lines) with the resolve chain -> 48.5 us. Two 32-row
// buffers = same 128 buffer-VGPRs as before (R4's spill was 2x64), but chunk
// c+1 loads fly during chunk c's resolve. PRE = 125 chunks exactly.
__device__ __forceinline__ void load_chunk(u64 (&buf)[32], const u64* col,
                                           int c, int lane) {
  bool act = lane >= (c >> 1);           // words < row>>6 never written
  const ulonglong2* p = (const ulonglong2*)(col + c*32);
  #pragma unroll
  for (int k = 0; k < 16; ++k) {
    ulonglong2 v; v.x = 0; v.y = 0;
    if (act) v = p[k];
    buf[2*k] = v.x; buf[2*k+1] = v.y;
  }
}

__device__ __forceinline__ void resolve_chunk(u64 (&buf)[32], int c, int lane,
                                              u64& removed, int& kc,
                                              int* __restrict__ sel_lds) {
  int wq = c >> 1;
  int base = (c & 1) * 32;               // bit window of word wq for this chunk
  u64 cur = removed, km = 0;
  #pragma unroll
  for (int jj = 0; jj < 32; ++jj) {
    if (((cur >> (base + jj)) & 1ull) == 0ull) {
      km |= (1ull << (base + jj));
      cur |= buf[jj];
    }
  }
  u64 kmw = __shfl(km, wq, 64);          // only lane wq's km is meaningful
  #pragma unroll
  for (int jj = 0; jj < 32; ++jj) {
    if ((kmw >> (base + jj)) & 1ull) removed |= buf[jj];
  }
  int sh = base + (lane & 31);           // <= 63: no UB shift
  bool mine = (lane < 32) && ((kmw >> sh) & 1ull);
  int pos = kc + (int)__popcll(kmw & ((1ull << sh) - 1ull));
  if (mine && pos < POST) sel_lds[pos] = c*32 + lane;
  kc += (int)__popcll(kmw);              // uniform across wave
}

__global__ __launch_bounds__(64) void k_reduce(const u64* __restrict__ mask,
                                               const float* __restrict__ crow,
                                               float* __restrict__ out) {
  __shared__ int sel_lds[POST];
  int b = blockIdx.x, lane = threadIdx.x;
  const u64* col = mask + ((size_t)b*MASKW + lane)*PRE;   // this lane's word-column
  u64 bufA[32], bufB[32];
  u64 removed = 0;
  int kc = 0;
  load_chunk(bufA, col, 0, lane);
  for (int c = 0; c < NCHUNK; c += 2) {
    if (c + 1 < NCHUNK) load_chunk(bufB, col, c + 1, lane);   // prefetch
    resolve_chunk(bufA, c, lane, removed, kc, sel_lds);
    if (kc >= POST) break;
    if (c + 1 >= NCHUNK) break;
    if (c + 2 < NCHUNK) load_chunk(bufA, col, c + 2, lane);   // prefetch
    resolve_chunk(bufB, c + 1, lane, removed, kc, sel_lds);
    if (kc >= POST) break;
  }
  __syncthreads();
  int kcap = kc < POST ? kc : POST;
  for (int r = lane; r < POST; r += 64) {
    float4 o0 = make_float4(0.f,0.f,0.f,0.f), o1 = o0;
    if (r < kcap) {
      int i = sel_lds[r];
      const float4* p = (const float4*)(crow + ((size_t)b*CAP + i)*8);
      o0 = p[0]; o1 = p[1];
    }
    float4* q = (float4*)(out + ((size_t)b*POST + r)*8);
    q[0] = o0; q[1] = o1;
  }
}

extern "C" void kernel_launch(void* const* d_in, const int* in_sizes, int n_in,
                              void* d_out, int out_size, void* d_ws, size_t ws_size,
                              hipStream_t stream) {
  const float* obj = (const float*)d_in[0];   // (N,)
  const float* reg = (const float*)d_in[1];   // (N,7)
  const float* anc = (const float*)d_in[2];   // (N,7)
  float* out = (float*)d_out;                 // (4,1000,8)
  char* ws = (char*)d_ws;

  int*  cntG = (int*)(ws + OFF_CNTG);
  int*  cntE = (int*)(ws + OFF_CNTE);
  u64*  keys = (u64*)(ws + OFF_KEYS);
  u32*  rank = (u32*)(ws + OFF_RANK);
  u32*  hc   = (u32*)(ws + OFF_HC);
  u32*  hf   = (u32*)(ws + OFF_HF);
  u32*  P1   = (u32*)(ws + OFF_P1);
  u32*  A1   = (u32*)(ws + OFF_A1);
  u32*  P2   = (u32*)(ws + OFF_P2);
  float* crow = (float*)(ws + OFF_CROW);
  float* nbox = (float*)(ws + OFF_NBOX);
  u64*  mask = (u64*)(ws + OFF_MASK);

  (void)hipMemsetAsync(ws, 0, ZERO_END, stream);   // counters + keys + rank

  k_hcoarse<<<NN/4096, 256, 0, stream>>>(obj, hc);
  k_res1<<<BB, 256, 0, stream>>>(hc, P1, A1);
  k_hfine<<<NN/4096, 256, 0, stream>>>(obj, P1, hf);
  k_res2<<<BB, 256, 0, stream>>>(hf, P1, A1, P2);
  k_compact<<<NN/4096, 256, 0, stream>>>(obj, P2, cntG, cntE, keys);
  k_rankp<<<dim3(CAPR/64, RSLICE, BB), 64, 0, stream>>>(keys, rank);
  k_decode<<<(BB*CAPR)/256, 256, 0, stream>>>(keys, rank, reg, anc, crow, nbox);
  k_mask<<<dim3(NBLK, 16, BB), 256, 0, stream>>>(nbox, mask);
  k_reduce<<<BB, 64, 0, stream>>>(mask, crow, out);
}